// Round 10
// baseline (442.587 us; speedup 1.0000x reference)
//
#include <hip/hip_runtime.h>
#include <hip/hip_bf16.h>
#include <cstdint>
#include <cstddef>

// Problem constants: X[S,B,D], W[3H,D], S=2048 B=16 D=1024 H=1024
#define S_LEN 2048
#define BATCH 16
#define DIM   1024
#define HID   1024
#define M_TOT (S_LEN * BATCH)   // 32768
#define N_TOT (3 * HID)         // 3072
#define K_TOT DIM               // 1024
#define NCHUNK 32
#define CHLEN (S_LEN / NCHUNK)  // 64

// GEMM geometry: 256x128 tile, BK=32, 4 waves (2M x 2N) of 128x64 wave-tiles,
// 16x16x32 MFMA, 2-slot dbuf (48 KiB LDS), ~208 regs -> 2 blocks/CU.
// Wave-tile 128x64 has LDS-read/MFMA ratio 83% (vs 62% for 64x64, round 9).
#define BM 256
#define BN 128
#define BK 32
#define NT (K_TOT / BK)          // 32 K-tiles
#define GRID_M (M_TOT / BM)      // 128
#define GRID_N (N_TOT / BN)      // 24
#define NWG (GRID_M * GRID_N)    // 3072 (divisible by 8)

typedef __bf16 bf16x8 __attribute__((ext_vector_type(8)));
typedef float  f32x4  __attribute__((ext_vector_type(4)));

__device__ __forceinline__ unsigned short f2bf(float f) {
    unsigned int u = __float_as_uint(f);
    u += 0x7FFFu + ((u >> 16) & 1u);   // RNE
    return (unsigned short)(u >> 16);
}
__device__ __forceinline__ float bf2f(unsigned int s) {
    return __uint_as_float(s << 16);
}
__device__ __forceinline__ float fast_sigmoid(float x) { return 1.0f / (1.0f + __expf(-x)); }
__device__ __forceinline__ float fast_tanh(float x)    { return 2.0f / (1.0f + __expf(-2.0f * x)) - 1.0f; }

// ---------------- fp32 -> bf16 conversion (X and W, one launch) ----------------
__global__ void __launch_bounds__(256) cvt_both(const float* __restrict__ X,
                                                const float* __restrict__ W,
                                                unsigned short* __restrict__ Xb,
                                                unsigned short* __restrict__ Wb) {
    const int nx = (M_TOT * K_TOT) / 4;   // float4 groups
    const int nw = (N_TOT * K_TOT) / 4;
    if (blockIdx.x < 2048) {
        for (int i = blockIdx.x * 256 + threadIdx.x; i < nx; i += 2048 * 256) {
            const float4 v = reinterpret_cast<const float4*>(X)[i];
            ushort4 o; o.x = f2bf(v.x); o.y = f2bf(v.y); o.z = f2bf(v.z); o.w = f2bf(v.w);
            reinterpret_cast<ushort4*>(Xb)[i] = o;
        }
    } else {
        for (int i = (blockIdx.x - 2048) * 256 + threadIdx.x; i < nw; i += 512 * 256) {
            const float4 v = reinterpret_cast<const float4*>(W)[i];
            ushort4 o; o.x = f2bf(v.x); o.y = f2bf(v.y); o.z = f2bf(v.z); o.w = f2bf(v.w);
            reinterpret_cast<ushort4*>(Wb)[i] = o;
        }
    }
}

// ---------------- GEMM: gates = act(X * W^T + b), bf16 out ----------------
#define GLOAD_LDS16(gp, lp)                                                         \
    __builtin_amdgcn_global_load_lds((__attribute__((address_space(1))) void*)(gp), \
                                     (__attribute__((address_space(3))) void*)(lp), 16, 0, 0)

__global__ void __launch_bounds__(256, 2)
gemm_gates(const unsigned short* __restrict__ Xb,
           const unsigned short* __restrict__ Wb,
           const float* __restrict__ bias,
           unsigned short* __restrict__ gates) {
    // 48 KiB: A[2 slots x 16 KiB] + B[2 slots x 8 KiB].
    // Epilogue reuses the first 32 KiB as a [128][128] bf16 half-C-tile (x2 passes).
    __shared__ __align__(16) unsigned short LDSbuf[2 * BM * BK + 2 * BN * BK];
#define AS(s) (LDSbuf + (s) * (BM * BK))
#define BS(s) (LDSbuf + 2 * (BM * BK) + (s) * (BN * BK))

    const int tid  = threadIdx.x;
    const int lane = tid & 63;
    const int wid  = tid >> 6;     // 0..3
    const int wm   = wid >> 1;     // 0..1  (wave out 128x64 at (wm*128, wn*64))
    const int wn   = wid & 1;      // 0..1
    const int lr   = lane & 15;
    const int lc   = lane >> 4;    // 0..3

    // XCD-aware bijective swizzle; bn-fastest -> X panel L2-resident per XCD
    const int swz = (blockIdx.x & 7) * (NWG / 8) + (blockIdx.x >> 3);
    const int bn = swz % GRID_N;
    const int bm = swz / GRID_N;

    // Staging (round-9 verbatim pattern): one issue = 256 thr x 16B = 64 rows x 64B.
    // Thread t: phys granule p=t&3 of row rl=t>>2; global col pre-swizzled
    // g = p ^ ((rl>>1)&3). Row offsets multiples of 64 preserve (rl>>1)&3.
    const int srow  = tid >> 2;                                  // 0..63
    const int scolE = (((tid & 3) ^ ((tid >> 3) & 3)) << 3);     // pre-swizzled col
    const unsigned short* gA = Xb + (size_t)(bm * BM + srow) * K_TOT + scolE;
    const unsigned short* gB = Wb + (size_t)(bn * BN + srow) * K_TOT + scolE;

    // Full-tile stage: 6 issues (A rows 0..255 in 4, B rows 0..127 in 2), slot t&1
#define STAGE_T(tt) do { const int _s = (tt) & 1; const int _k = (tt) * BK;          \
        GLOAD_LDS16(gA + _k,                 AS(_s) + tid * 8);                      \
        GLOAD_LDS16(gA + 64 * K_TOT + _k,    AS(_s) + 2048 + tid * 8);               \
        GLOAD_LDS16(gA + 128 * K_TOT + _k,   AS(_s) + 4096 + tid * 8);               \
        GLOAD_LDS16(gA + 192 * K_TOT + _k,   AS(_s) + 6144 + tid * 8);               \
        GLOAD_LDS16(gB + _k,                 BS(_s) + tid * 8);                      \
        GLOAD_LDS16(gB + 64 * K_TOT + _k,    BS(_s) + 2048 + tid * 8);               \
    } while (0)

    f32x4 acc[8][4];
#pragma unroll
    for (int m = 0; m < 8; ++m)
#pragma unroll
        for (int n = 0; n < 4; ++n) acc[m][n] = {0.0f, 0.0f, 0.0f, 0.0f};

    // Prologue: stage tiles 0,1 (12 loads); vmcnt(6) -> tile 0 resident
    STAGE_T(0); STAGE_T(1);
    asm volatile("s_waitcnt vmcnt(6)" ::: "memory");
    __builtin_amdgcn_s_barrier();

#pragma unroll 2
    for (int t = 0; t < NT; ++t) {
        const int s = t & 1;
        // Fragment reads (round-2 verbatim geometry, measured 0 conflicts):
        // 8 A + 4 B ds_read_b128 per wave.
        bf16x8 av[8], bv[4];
#pragma unroll
        for (int m = 0; m < 8; ++m) {
            const int row = wm * 128 + m * 16 + lr;
            av[m] = *reinterpret_cast<const bf16x8*>(
                &AS(s)[row * BK + ((lc ^ ((row >> 1) & 3)) << 3)]);
        }
#pragma unroll
        for (int n = 0; n < 4; ++n) {
            const int row = wn * 64 + n * 16 + lr;
            bv[n] = *reinterpret_cast<const bf16x8*>(
                &BS(s)[row * BK + ((lc ^ ((row >> 1) & 3)) << 3)]);
        }
        // Reads retired -> slot s reusable by the next stage
        asm volatile("s_waitcnt lgkmcnt(0)" ::: "memory");
        __builtin_amdgcn_sched_barrier(0);
        __builtin_amdgcn_s_barrier();
        if (t + 2 < NT) STAGE_T(t + 2);
        __builtin_amdgcn_s_setprio(1);
#pragma unroll
        for (int m = 0; m < 8; ++m)
#pragma unroll
            for (int n = 0; n < 4; ++n)
                acc[m][n] = __builtin_amdgcn_mfma_f32_16x16x32_bf16(av[m], bv[n], acc[m][n], 0, 0, 0);
        __builtin_amdgcn_s_setprio(0);
        // Counted wait: tile t+1 resident before next iteration reads it
        if (t + 2 < NT) {
            asm volatile("s_waitcnt vmcnt(6)" ::: "memory");   // in-flight 12 -> retire t+1
        } else if (t + 1 < NT) {
            asm volatile("s_waitcnt vmcnt(0)" ::: "memory");
        }
        __builtin_amdgcn_s_barrier();
    }
#undef STAGE_T

    // ---- Epilogue: two half-passes (rows [p*128, p*128+128)); round-9-proven
    // 128x128 LDS restage, 256B-contiguous stores (write amplification 1x).
    // acc C/D mapping (proven): col = lane&15 (+nf*16+wn*64), row = (lane>>4)*4+reg.
    const int gate_id = bn >> 3;  // 0:tanh(Z) 1:sig(F) 2:sig(O), uniform per block
    const int gr = tid & 15;      // 16B granule within 256B row
    const int rb = tid >> 4;      // 0..15
#pragma unroll
    for (int p = 0; p < 2; ++p) {
        if (wm == p) {   // wave-uniform: 2 waves (wn=0,1) scatter 128x128
            const int rl0 = (lane >> 4) << 2;
            const int cl0 = wn * 64 + lr;
#pragma unroll
            for (int nf = 0; nf < 4; ++nf) {
                const int col = cl0 + nf * 16;
                const float bb = bias[bn * BN + col];
#pragma unroll
                for (int mf = 0; mf < 8; ++mf) {
#pragma unroll
                    for (int r = 0; r < 4; ++r) {
                        const int rl = rl0 + mf * 16 + r;      // local row 0..127
                        const float y = acc[mf][nf][r] + bb;
                        const float g = (gate_id == 0) ? fast_tanh(y) : fast_sigmoid(y);
                        const int phys = (col >> 3) ^ (rl & 7);
                        LDSbuf[rl * 128 + (phys << 3) + (col & 7)] = f2bf(g);
                    }
                }
            }
        }
        asm volatile("s_waitcnt lgkmcnt(0)" ::: "memory");
        __builtin_amdgcn_sched_barrier(0);
        __builtin_amdgcn_s_barrier();
        // All 4 waves copy out 128 rows x 256B (256B contiguous per 16 lanes)
#pragma unroll
        for (int i = 0; i < 8; ++i) {
            const int rl = i * 16 + rb;
            const int phys = gr ^ (rl & 7);
            const bf16x8 v = *reinterpret_cast<const bf16x8*>(&LDSbuf[rl * 128 + (phys << 3)]);
            *reinterpret_cast<bf16x8*>(
                &gates[(size_t)(bm * BM + p * 128 + rl) * N_TOT + bn * BN + gr * 8]) = v;
        }
        if (p == 0) {   // copy reads done before pass-1 scatter overwrites
            asm volatile("s_waitcnt lgkmcnt(0)" ::: "memory");
            __builtin_amdgcn_sched_barrier(0);
            __builtin_amdgcn_s_barrier();
        }
    }
#undef AS
#undef BS
}

// ---------------- chunked linear scan (fo-pool), vec2 over h ----------------
__global__ void __launch_bounds__(256) scan_phase1(const unsigned short* __restrict__ gates,
                                                   float* __restrict__ Aprod,
                                                   float* __restrict__ Cend) {
    const int t = blockIdx.x * 256 + threadIdx.x;  // chunk*8192 + b*512 + hp
    const int hp = t & 511;
    const int b  = (t >> 9) & (BATCH - 1);
    const int chunk = t >> 13;
    float c0 = 0.f, c1 = 0.f, a0 = 1.f, a1 = 1.f;
    const int m0 = chunk * (CHLEN * BATCH) + b;
    const unsigned short* gz = gates + (size_t)m0 * N_TOT + hp * 2;
#pragma unroll 4
    for (int i = 0; i < CHLEN; ++i) {
        const unsigned short* p = gz + (size_t)i * BATCH * N_TOT;
        const unsigned int zz = *reinterpret_cast<const unsigned int*>(p);
        const unsigned int ff = *reinterpret_cast<const unsigned int*>(p + HID);
        const float z0 = bf2f(zz & 0xffffu), z1 = bf2f(zz >> 16);
        const float f0 = bf2f(ff & 0xffffu), f1 = bf2f(ff >> 16);
        const float o0 = 1.f - f0, o1 = 1.f - f1;
        c0 = f0 * z0 + o0 * c0;  c1 = f1 * z1 + o1 * c1;
        a0 *= o0;                a1 *= o1;
    }
    const int idx = chunk * (BATCH * HID) + b * HID + hp * 2;
    *reinterpret_cast<float2*>(&Aprod[idx]) = make_float2(a0, a1);
    *reinterpret_cast<float2*>(&Cend[idx])  = make_float2(c0, c1);
}

__global__ void __launch_bounds__(256) scan_combine(const float* __restrict__ Aprod,
                                                    const float* __restrict__ Cend,
                                                    const float* __restrict__ hidden,
                                                    float* __restrict__ Cstart,
                                                    float* __restrict__ c_last) {
    const int t = blockIdx.x * 256 + threadIdx.x;  // b*1024 + h
    float c = hidden[t];
#pragma unroll
    for (int j = 0; j < NCHUNK; ++j) {
        const int idx = j * (BATCH * HID) + t;
        Cstart[idx] = c;
        c = Aprod[idx] * c + Cend[idx];
    }
    c_last[t] = c;
}

__global__ void __launch_bounds__(256) scan_phase3(const unsigned short* __restrict__ gates,
                                                   const float* __restrict__ Cstart,
                                                   float* __restrict__ Hout) {
    const int t = blockIdx.x * 256 + threadIdx.x;
    const int hp = t & 511;
    const int b  = (t >> 9) & (BATCH - 1);
    const int chunk = t >> 13;
    const int idx = chunk * (BATCH * HID) + b * HID + hp * 2;
    float2 cs = *reinterpret_cast<const float2*>(&Cstart[idx]);
    float c0 = cs.x, c1 = cs.y;
    const int m0 = chunk * (CHLEN * BATCH) + b;
    const unsigned short* gz = gates + (size_t)m0 * N_TOT + hp * 2;
#pragma unroll 4
    for (int i = 0; i < CHLEN; ++i) {
        const unsigned short* p = gz + (size_t)i * BATCH * N_TOT;
        const unsigned int zz = *reinterpret_cast<const unsigned int*>(p);
        const unsigned int ff = *reinterpret_cast<const unsigned int*>(p + HID);
        const unsigned int oo = *reinterpret_cast<const unsigned int*>(p + 2 * HID);
        const float z0 = bf2f(zz & 0xffffu), z1 = bf2f(zz >> 16);
        const float f0 = bf2f(ff & 0xffffu), f1 = bf2f(ff >> 16);
        const float g0 = bf2f(oo & 0xffffu), g1 = bf2f(oo >> 16);
        c0 = f0 * z0 + (1.f - f0) * c0;
        c1 = f1 * z1 + (1.f - f1) * c1;
        const int m = m0 + i * BATCH;
        *reinterpret_cast<float2*>(&Hout[(size_t)m * HID + hp * 2]) = make_float2(g0 * c0, g1 * c1);
    }
}

// ---------------- launch ----------------
extern "C" void kernel_launch(void* const* d_in, const int* in_sizes, int n_in,
                              void* d_out, int out_size, void* d_ws, size_t ws_size,
                              hipStream_t stream) {
    const float* X      = (const float*)d_in[0];
    const float* hidden = (const float*)d_in[1];
    const float* W      = (const float*)d_in[2];
    const float* bias   = (const float*)d_in[3];
    float* out    = (float*)d_out;
    float* c_last = out + (size_t)M_TOT * HID;   // outputs: H_out then C[-1:]

    char* ws = (char*)d_ws;
    unsigned short* Xb    = (unsigned short*)ws;                                // 64 MiB
    unsigned short* Wb    = (unsigned short*)(ws + (size_t)M_TOT * K_TOT * 2);  // 6 MiB
    unsigned short* gates = Wb + (size_t)N_TOT * K_TOT;                         // 192 MiB bf16
    float* Aprod  = (float*)(gates + (size_t)M_TOT * N_TOT);
    float* Cend   = Aprod + (size_t)NCHUNK * BATCH * HID;
    float* Cstart = Cend  + (size_t)NCHUNK * BATCH * HID;

    cvt_both<<<dim3(2560), dim3(256), 0, stream>>>(X, W, Xb, Wb);
    gemm_gates<<<dim3(NWG), dim3(256), 0, stream>>>(Xb, Wb, bias, gates);
    scan_phase1<<<dim3(1024), dim3(256), 0, stream>>>(gates, Aprod, Cend);
    scan_combine<<<dim3(64), dim3(256), 0, stream>>>(Aprod, Cend, hidden, Cstart, c_last);
    scan_phase3<<<dim3(1024), dim3(256), 0, stream>>>(gates, Cstart, out);
}

// Round 11
// 391.600 us; speedup vs baseline: 1.1302x; 1.1302x over previous
//
#include <hip/hip_runtime.h>
#include <hip/hip_bf16.h>
#include <cstdint>
#include <cstddef>

// Problem constants: X[S,B,D], W[3H,D], S=2048 B=16 D=1024 H=1024
#define S_LEN 2048
#define BATCH 16
#define DIM   1024
#define HID   1024
#define M_TOT (S_LEN * BATCH)   // 32768
#define N_TOT (3 * HID)         // 3072
#define K_TOT DIM               // 1024
#define NCHUNK 32
#define CHLEN (S_LEN / NCHUNK)  // 64

// GEMM geometry: 128x128 tile, BK=32, 4 waves (2x2), 16x16x32 MFMA,
// 2-slot dbuf (32 KiB LDS), 64 VGPR + 64 AGPR = 128 regs/wave
// -> __launch_bounds__(256,4): 4 waves/SIMD = 4 blocks/CU.
#define BM 128
#define BN 128
#define BK 32
#define NT (K_TOT / BK)          // 32 K-tiles
#define GRID_M (M_TOT / BM)      // 256
#define GRID_N (N_TOT / BN)      // 24
#define NWG (GRID_M * GRID_N)    // 6144 (divisible by 8)

typedef __bf16 bf16x8 __attribute__((ext_vector_type(8)));
typedef float  f32x4  __attribute__((ext_vector_type(4)));

__device__ __forceinline__ unsigned short f2bf(float f) {
    unsigned int u = __float_as_uint(f);
    u += 0x7FFFu + ((u >> 16) & 1u);   // RNE
    return (unsigned short)(u >> 16);
}
__device__ __forceinline__ float bf2f(unsigned int s) {
    return __uint_as_float(s << 16);
}
__device__ __forceinline__ float fast_sigmoid(float x) { return 1.0f / (1.0f + __expf(-x)); }
__device__ __forceinline__ float fast_tanh(float x)    { return 2.0f / (1.0f + __expf(-2.0f * x)) - 1.0f; }

// ---------------- fp32 -> bf16 conversion (X and W, one launch) ----------------
__global__ void __launch_bounds__(256) cvt_both(const float* __restrict__ X,
                                                const float* __restrict__ W,
                                                unsigned short* __restrict__ Xb,
                                                unsigned short* __restrict__ Wb) {
    const int nx = (M_TOT * K_TOT) / 4;   // float4 groups
    const int nw = (N_TOT * K_TOT) / 4;
    if (blockIdx.x < 2048) {
        for (int i = blockIdx.x * 256 + threadIdx.x; i < nx; i += 2048 * 256) {
            const float4 v = reinterpret_cast<const float4*>(X)[i];
            ushort4 o; o.x = f2bf(v.x); o.y = f2bf(v.y); o.z = f2bf(v.z); o.w = f2bf(v.w);
            reinterpret_cast<ushort4*>(Xb)[i] = o;
        }
    } else {
        for (int i = (blockIdx.x - 2048) * 256 + threadIdx.x; i < nw; i += 512 * 256) {
            const float4 v = reinterpret_cast<const float4*>(W)[i];
            ushort4 o; o.x = f2bf(v.x); o.y = f2bf(v.y); o.z = f2bf(v.z); o.w = f2bf(v.w);
            reinterpret_cast<ushort4*>(Wb)[i] = o;
        }
    }
}

// ---------------- GEMM: gates = act(X * W^T + b), bf16 out ----------------
// Round-9 kernel byte-identical except __launch_bounds__(256,4): the 4th
// wave/SIMD (4 blocks/CU) hides the VALU/barrier stalls (VALUBusy 42% >
// MfmaUtil 35% at 3 waves/SIMD; 128 regs/wave makes 4 feasible).
#define GLOAD_LDS16(gp, lp)                                                         \
    __builtin_amdgcn_global_load_lds((__attribute__((address_space(1))) void*)(gp), \
                                     (__attribute__((address_space(3))) void*)(lp), 16, 0, 0)

__global__ void __launch_bounds__(256, 4)
gemm_gates(const unsigned short* __restrict__ Xb,
           const unsigned short* __restrict__ Wb,
           const float* __restrict__ bias,
           unsigned short* __restrict__ gates) {
    // 32 KiB: [A slot0 | A slot1 | B slot0 | B slot1], each 8 KiB.
    // Epilogue reuses the whole buffer as a [128][128] bf16 C-tile.
    __shared__ __align__(16) unsigned short LDSbuf[4 * BM * BK];
#define AS(s) (LDSbuf + (s) * (BM * BK))
#define BS(s) (LDSbuf + 2 * (BM * BK) + (s) * (BN * BK))

    const int tid  = threadIdx.x;
    const int lane = tid & 63;
    const int wid  = tid >> 6;     // 0..3
    const int wm   = wid >> 1;     // 0..1  (wave out 64x64 at (wm*64, wn*64))
    const int wn   = wid & 1;      // 0..1
    const int lr   = lane & 15;
    const int lc   = lane >> 4;    // 0..3

    // XCD-aware bijective swizzle; bn-fastest -> X panel L2-resident per XCD
    const int swz = (blockIdx.x & 7) * (NWG / 8) + (blockIdx.x >> 3);
    const int bn = swz % GRID_N;
    const int bm = swz / GRID_N;

    // Staging (round-9 verbatim): one issue = 256 thr x 16B = 64 rows x 64B.
    // Thread t: phys granule p=t&3 of row rl=t>>2; global col pre-swizzled
    // g = p ^ ((rl>>1)&3). Row offset +64 preserves (rl>>1)&3.
    const int srow  = tid >> 2;                                  // 0..63
    const int scolE = (((tid & 3) ^ ((tid >> 3) & 3)) << 3);     // pre-swizzled col
    const unsigned short* gA = Xb + (size_t)(bm * BM + srow) * K_TOT + scolE;
    const unsigned short* gB = Wb + (size_t)(bn * BN + srow) * K_TOT + scolE;

    // Full-tile stage: 4 issues (A rows 0-63/64-127, B likewise) into slot t&1
#define STAGE_T(tt) do { const int _s = (tt) & 1; const int _k = (tt) * BK;          \
        GLOAD_LDS16(gA + _k,                AS(_s) + tid * 8);                       \
        GLOAD_LDS16(gA + 64 * K_TOT + _k,   AS(_s) + 2048 + tid * 8);                \
        GLOAD_LDS16(gB + _k,                BS(_s) + tid * 8);                       \
        GLOAD_LDS16(gB + 64 * K_TOT + _k,   BS(_s) + 2048 + tid * 8);                \
    } while (0)

    f32x4 acc[4][4];
#pragma unroll
    for (int m = 0; m < 4; ++m)
#pragma unroll
        for (int n = 0; n < 4; ++n) acc[m][n] = {0.0f, 0.0f, 0.0f, 0.0f};

    // Prologue: stage tiles 0,1 (8 loads); vmcnt(4) -> tile 0 resident
    STAGE_T(0); STAGE_T(1);
    asm volatile("s_waitcnt vmcnt(4)" ::: "memory");
    __builtin_amdgcn_s_barrier();

#pragma unroll 2
    for (int t = 0; t < NT; ++t) {
        const int s = t & 1;
        // Fragment reads (round-2 verbatim, measured 0 conflicts): 4 A + 4 B b128
        bf16x8 av[4], bv[4];
#pragma unroll
        for (int m = 0; m < 4; ++m) {
            const int row = wm * 64 + m * 16 + lr;
            av[m] = *reinterpret_cast<const bf16x8*>(
                &AS(s)[row * BK + ((lc ^ ((row >> 1) & 3)) << 3)]);
        }
#pragma unroll
        for (int n = 0; n < 4; ++n) {
            const int row = wn * 64 + n * 16 + lr;
            bv[n] = *reinterpret_cast<const bf16x8*>(
                &BS(s)[row * BK + ((lc ^ ((row >> 1) & 3)) << 3)]);
        }
        // Reads retired -> slot s reusable by the next stage
        asm volatile("s_waitcnt lgkmcnt(0)" ::: "memory");
        __builtin_amdgcn_sched_barrier(0);
        __builtin_amdgcn_s_barrier();
        if (t + 2 < NT) STAGE_T(t + 2);
        __builtin_amdgcn_s_setprio(1);
#pragma unroll
        for (int m = 0; m < 4; ++m)
#pragma unroll
            for (int n = 0; n < 4; ++n)
                acc[m][n] = __builtin_amdgcn_mfma_f32_16x16x32_bf16(av[m], bv[n], acc[m][n], 0, 0, 0);
        __builtin_amdgcn_s_setprio(0);
        // Counted wait: tile t+1 resident before next iteration reads it
        if (t + 2 < NT) {
            asm volatile("s_waitcnt vmcnt(4)" ::: "memory");   // in-flight 8 -> retire t+1
        } else if (t + 1 < NT) {
            asm volatile("s_waitcnt vmcnt(0)" ::: "memory");
        }
        __builtin_amdgcn_s_barrier();
    }
#undef STAGE_T

    // ---- Epilogue: bias + activation + LDS restage (round-9-proven), then
    // 256B-contiguous stores (write amplification 1x).
    // acc C/D mapping (proven): col = lane&15 (+nf*16+wn*64), row = (lane>>4)*4+reg.
    const int gate_id = bn >> 3;  // 0:tanh(Z) 1:sig(F) 2:sig(O), uniform per block
    {
        const int rl0 = wm * 64 + ((lane >> 4) << 2);
        const int cl0 = wn * 64 + lr;
#pragma unroll
        for (int nf = 0; nf < 4; ++nf) {
            const int col = cl0 + nf * 16;
            const float bb = bias[bn * BN + col];
#pragma unroll
            for (int mf = 0; mf < 4; ++mf) {
#pragma unroll
                for (int r = 0; r < 4; ++r) {
                    const int rl = rl0 + mf * 16 + r;          // local row 0..127
                    const float y = acc[mf][nf][r] + bb;
                    const float g = (gate_id == 0) ? fast_tanh(y) : fast_sigmoid(y);
                    const int phys = (col >> 3) ^ (rl & 7);    // 16B granule 0..15
                    LDSbuf[rl * 128 + (phys << 3) + (col & 7)] = f2bf(g);
                }
            }
        }
    }
    asm volatile("s_waitcnt lgkmcnt(0)" ::: "memory");
    __builtin_amdgcn_sched_barrier(0);
    __builtin_amdgcn_s_barrier();
    // Copy out: 128 rows x 256B; per instruction 4 rows x 256B contiguous.
    {
        const int gr = tid & 15;    // 16B granule within row
        const int rb = tid >> 4;    // 0..15
#pragma unroll
        for (int i = 0; i < 8; ++i) {
            const int rl = i * 16 + rb;
            const int phys = gr ^ (rl & 7);
            const bf16x8 v = *reinterpret_cast<const bf16x8*>(&LDSbuf[rl * 128 + (phys << 3)]);
            *reinterpret_cast<bf16x8*>(
                &gates[(size_t)(bm * BM + rl) * N_TOT + bn * BN + gr * 8]) = v;
        }
    }
#undef AS
#undef BS
}

// ---------------- chunked linear scan (fo-pool), vec2 over h ----------------
__global__ void __launch_bounds__(256) scan_phase1(const unsigned short* __restrict__ gates,
                                                   float* __restrict__ Aprod,
                                                   float* __restrict__ Cend) {
    const int t = blockIdx.x * 256 + threadIdx.x;  // chunk*8192 + b*512 + hp
    const int hp = t & 511;
    const int b  = (t >> 9) & (BATCH - 1);
    const int chunk = t >> 13;
    float c0 = 0.f, c1 = 0.f, a0 = 1.f, a1 = 1.f;
    const int m0 = chunk * (CHLEN * BATCH) + b;
    const unsigned short* gz = gates + (size_t)m0 * N_TOT + hp * 2;
#pragma unroll 4
    for (int i = 0; i < CHLEN; ++i) {
        const unsigned short* p = gz + (size_t)i * BATCH * N_TOT;
        const unsigned int zz = *reinterpret_cast<const unsigned int*>(p);
        const unsigned int ff = *reinterpret_cast<const unsigned int*>(p + HID);
        const float z0 = bf2f(zz & 0xffffu), z1 = bf2f(zz >> 16);
        const float f0 = bf2f(ff & 0xffffu), f1 = bf2f(ff >> 16);
        const float o0 = 1.f - f0, o1 = 1.f - f1;
        c0 = f0 * z0 + o0 * c0;  c1 = f1 * z1 + o1 * c1;
        a0 *= o0;                a1 *= o1;
    }
    const int idx = chunk * (BATCH * HID) + b * HID + hp * 2;
    *reinterpret_cast<float2*>(&Aprod[idx]) = make_float2(a0, a1);
    *reinterpret_cast<float2*>(&Cend[idx])  = make_float2(c0, c1);
}

__global__ void __launch_bounds__(256) scan_combine(const float* __restrict__ Aprod,
                                                    const float* __restrict__ Cend,
                                                    const float* __restrict__ hidden,
                                                    float* __restrict__ Cstart,
                                                    float* __restrict__ c_last) {
    const int t = blockIdx.x * 256 + threadIdx.x;  // b*1024 + h
    float c = hidden[t];
#pragma unroll
    for (int j = 0; j < NCHUNK; ++j) {
        const int idx = j * (BATCH * HID) + t;
        Cstart[idx] = c;
        c = Aprod[idx] * c + Cend[idx];
    }
    c_last[t] = c;
}

__global__ void __launch_bounds__(256) scan_phase3(const unsigned short* __restrict__ gates,
                                                   const float* __restrict__ Cstart,
                                                   float* __restrict__ Hout) {
    const int t = blockIdx.x * 256 + threadIdx.x;
    const int hp = t & 511;
    const int b  = (t >> 9) & (BATCH - 1);
    const int chunk = t >> 13;
    const int idx = chunk * (BATCH * HID) + b * HID + hp * 2;
    float2 cs = *reinterpret_cast<const float2*>(&Cstart[idx]);
    float c0 = cs.x, c1 = cs.y;
    const int m0 = chunk * (CHLEN * BATCH) + b;
    const unsigned short* gz = gates + (size_t)m0 * N_TOT + hp * 2;
#pragma unroll 4
    for (int i = 0; i < CHLEN; ++i) {
        const unsigned short* p = gz + (size_t)i * BATCH * N_TOT;
        const unsigned int zz = *reinterpret_cast<const unsigned int*>(p);
        const unsigned int ff = *reinterpret_cast<const unsigned int*>(p + HID);
        const unsigned int oo = *reinterpret_cast<const unsigned int*>(p + 2 * HID);
        const float z0 = bf2f(zz & 0xffffu), z1 = bf2f(zz >> 16);
        const float f0 = bf2f(ff & 0xffffu), f1 = bf2f(ff >> 16);
        const float g0 = bf2f(oo & 0xffffu), g1 = bf2f(oo >> 16);
        c0 = f0 * z0 + (1.f - f0) * c0;
        c1 = f1 * z1 + (1.f - f1) * c1;
        const int m = m0 + i * BATCH;
        *reinterpret_cast<float2*>(&Hout[(size_t)m * HID + hp * 2]) = make_float2(g0 * c0, g1 * c1);
    }
}

// ---------------- launch ----------------
extern "C" void kernel_launch(void* const* d_in, const int* in_sizes, int n_in,
                              void* d_out, int out_size, void* d_ws, size_t ws_size,
                              hipStream_t stream) {
    const float* X      = (const float*)d_in[0];
    const float* hidden = (const float*)d_in[1];
    const float* W      = (const float*)d_in[2];
    const float* bias   = (const float*)d_in[3];
    float* out    = (float*)d_out;
    float* c_last = out + (size_t)M_TOT * HID;   // outputs: H_out then C[-1:]

    char* ws = (char*)d_ws;
    unsigned short* Xb    = (unsigned short*)ws;                                // 64 MiB
    unsigned short* Wb    = (unsigned short*)(ws + (size_t)M_TOT * K_TOT * 2);  // 6 MiB
    unsigned short* gates = Wb + (size_t)N_TOT * K_TOT;                         // 192 MiB bf16
    float* Aprod  = (float*)(gates + (size_t)M_TOT * N_TOT);
    float* Cend   = Aprod + (size_t)NCHUNK * BATCH * HID;
    float* Cstart = Cend  + (size_t)NCHUNK * BATCH * HID;

    cvt_both<<<dim3(2560), dim3(256), 0, stream>>>(X, W, Xb, Wb);
    gemm_gates<<<dim3(NWG), dim3(256), 0, stream>>>(Xb, Wb, bias, gates);
    scan_phase1<<<dim3(1024), dim3(256), 0, stream>>>(gates, Aprod, Cend);
    scan_combine<<<dim3(64), dim3(256), 0, stream>>>(Aprod, Cend, hidden, Cstart, c_last);
    scan_phase3<<<dim3(1024), dim3(256), 0, stream>>>(gates, Cstart, out);
}

// Round 12
// 380.376 us; speedup vs baseline: 1.1636x; 1.0295x over previous
//
#include <hip/hip_runtime.h>
#include <hip/hip_bf16.h>
#include <cstdint>
#include <cstddef>

// Problem constants: X[S,B,D], W[3H,D], S=2048 B=16 D=1024 H=1024
#define S_LEN 2048
#define BATCH 16
#define DIM   1024
#define HID   1024
#define M_TOT (S_LEN * BATCH)   // 32768
#define N_TOT (3 * HID)         // 3072
#define K_TOT DIM               // 1024
#define NCHUNK 32
#define CHLEN (S_LEN / NCHUNK)  // 64

// GEMM geometry: 128x128 tile, BK=32, 4 waves (2x2), 16x16x32 MFMA,
// 2-slot dbuf (32 KiB LDS), 64 VGPR + 64 AGPR = 128 regs/wave.
#define BM 128
#define BN 128
#define BK 32
#define NT (K_TOT / BK)          // 32 K-tiles
#define GRID_M (M_TOT / BM)      // 256
#define GRID_N (N_TOT / BN)      // 24
#define NWG (GRID_M * GRID_N)    // 6144 (divisible by 8)

typedef __bf16 bf16x8 __attribute__((ext_vector_type(8)));
typedef float  f32x4  __attribute__((ext_vector_type(4)));

__device__ __forceinline__ unsigned short f2bf(float f) {
    unsigned int u = __float_as_uint(f);
    u += 0x7FFFu + ((u >> 16) & 1u);   // RNE
    return (unsigned short)(u >> 16);
}
__device__ __forceinline__ float bf2f(unsigned int s) {
    return __uint_as_float(s << 16);
}
__device__ __forceinline__ float fast_sigmoid(float x) { return 1.0f / (1.0f + __expf(-x)); }
__device__ __forceinline__ float fast_tanh(float x)    { return 2.0f / (1.0f + __expf(-2.0f * x)) - 1.0f; }

// ---------------- fp32 -> bf16 conversion (X and W, one launch) ----------------
__global__ void __launch_bounds__(256) cvt_both(const float* __restrict__ X,
                                                const float* __restrict__ W,
                                                unsigned short* __restrict__ Xb,
                                                unsigned short* __restrict__ Wb) {
    const int nx = (M_TOT * K_TOT) / 4;   // float4 groups
    const int nw = (N_TOT * K_TOT) / 4;
    if (blockIdx.x < 2048) {
        for (int i = blockIdx.x * 256 + threadIdx.x; i < nx; i += 2048 * 256) {
            const float4 v = reinterpret_cast<const float4*>(X)[i];
            ushort4 o; o.x = f2bf(v.x); o.y = f2bf(v.y); o.z = f2bf(v.z); o.w = f2bf(v.w);
            reinterpret_cast<ushort4*>(Xb)[i] = o;
        }
    } else {
        for (int i = (blockIdx.x - 2048) * 256 + threadIdx.x; i < nw; i += 512 * 256) {
            const float4 v = reinterpret_cast<const float4*>(W)[i];
            ushort4 o; o.x = f2bf(v.x); o.y = f2bf(v.y); o.z = f2bf(v.z); o.w = f2bf(v.w);
            reinterpret_cast<ushort4*>(Wb)[i] = o;
        }
    }
}

// ---------------- GEMM: gates = act(X * W^T + b), bf16 out ----------------
// Round-11 kernel, single change: grouped rasterization (8bm x 4bn bands per
// XCD chunk, band_m-major) so the concurrent working set (8 A + 4 B panels
// = 3 MB) fits the 4 MB per-XCD L2 -> staged loads hit L2 (~200cy) instead of
// HBM (~900cy), which the 1-tile prefetch depth can actually cover.
#define GLOAD_LDS16(gp, lp)                                                         \
    __builtin_amdgcn_global_load_lds((__attribute__((address_space(1))) void*)(gp), \
                                     (__attribute__((address_space(3))) void*)(lp), 16, 0, 0)

__global__ void __launch_bounds__(256, 4)
gemm_gates(const unsigned short* __restrict__ Xb,
           const unsigned short* __restrict__ Wb,
           const float* __restrict__ bias,
           unsigned short* __restrict__ gates) {
    // 32 KiB: [A slot0 | A slot1 | B slot0 | B slot1], each 8 KiB.
    // Epilogue reuses the whole buffer as a [128][128] bf16 C-tile.
    __shared__ __align__(16) unsigned short LDSbuf[4 * BM * BK];
#define AS(s) (LDSbuf + (s) * (BM * BK))
#define BS(s) (LDSbuf + 2 * (BM * BK) + (s) * (BN * BK))

    const int tid  = threadIdx.x;
    const int lane = tid & 63;
    const int wid  = tid >> 6;     // 0..3
    const int wm   = wid >> 1;     // 0..1  (wave out 64x64 at (wm*64, wn*64))
    const int wn   = wid & 1;      // 0..1
    const int lr   = lane & 15;
    const int lc   = lane >> 4;    // 0..3

    // XCD-aware grouped rasterization (bijective):
    // xcd chunk = 768 blocks = bm band [xcd*32, xcd*32+32) x all 24 bn.
    // Within chunk: groups of 32 = 8bm x 4bn; band_m-major group order keeps
    // each 2 MB A-band L2-resident across 6 consecutive groups.
    const int xcd   = blockIdx.x & 7;
    const int idx   = blockIdx.x >> 3;        // 0..767
    const int grp   = idx >> 5;               // 0..23
    const int w32   = idx & 31;               // 0..31
    const int bandm = grp / 6;                // 0..3
    const int bandn = grp % 6;                // 0..5
    const int bm = xcd * 32 + bandm * 8 + (w32 >> 2);   // 0..255
    const int bn = bandn * 4 + (w32 & 3);               // 0..23

    // Staging (round-9 verbatim): one issue = 256 thr x 16B = 64 rows x 64B.
    // Thread t: phys granule p=t&3 of row rl=t>>2; global col pre-swizzled
    // g = p ^ ((rl>>1)&3). Row offset +64 preserves (rl>>1)&3.
    const int srow  = tid >> 2;                                  // 0..63
    const int scolE = (((tid & 3) ^ ((tid >> 3) & 3)) << 3);     // pre-swizzled col
    const unsigned short* gA = Xb + (size_t)(bm * BM + srow) * K_TOT + scolE;
    const unsigned short* gB = Wb + (size_t)(bn * BN + srow) * K_TOT + scolE;

    // Full-tile stage: 4 issues (A rows 0-63/64-127, B likewise) into slot t&1
#define STAGE_T(tt) do { const int _s = (tt) & 1; const int _k = (tt) * BK;          \
        GLOAD_LDS16(gA + _k,                AS(_s) + tid * 8);                       \
        GLOAD_LDS16(gA + 64 * K_TOT + _k,   AS(_s) + 2048 + tid * 8);                \
        GLOAD_LDS16(gB + _k,                BS(_s) + tid * 8);                       \
        GLOAD_LDS16(gB + 64 * K_TOT + _k,   BS(_s) + 2048 + tid * 8);                \
    } while (0)

    f32x4 acc[4][4];
#pragma unroll
    for (int m = 0; m < 4; ++m)
#pragma unroll
        for (int n = 0; n < 4; ++n) acc[m][n] = {0.0f, 0.0f, 0.0f, 0.0f};

    // Prologue: stage tiles 0,1 (8 loads); vmcnt(4) -> tile 0 resident
    STAGE_T(0); STAGE_T(1);
    asm volatile("s_waitcnt vmcnt(4)" ::: "memory");
    __builtin_amdgcn_s_barrier();

#pragma unroll 2
    for (int t = 0; t < NT; ++t) {
        const int s = t & 1;
        // Fragment reads (round-2 verbatim, measured 0 conflicts): 4 A + 4 B b128
        bf16x8 av[4], bv[4];
#pragma unroll
        for (int m = 0; m < 4; ++m) {
            const int row = wm * 64 + m * 16 + lr;
            av[m] = *reinterpret_cast<const bf16x8*>(
                &AS(s)[row * BK + ((lc ^ ((row >> 1) & 3)) << 3)]);
        }
#pragma unroll
        for (int n = 0; n < 4; ++n) {
            const int row = wn * 64 + n * 16 + lr;
            bv[n] = *reinterpret_cast<const bf16x8*>(
                &BS(s)[row * BK + ((lc ^ ((row >> 1) & 3)) << 3)]);
        }
        // Reads retired -> slot s reusable by the next stage
        asm volatile("s_waitcnt lgkmcnt(0)" ::: "memory");
        __builtin_amdgcn_sched_barrier(0);
        __builtin_amdgcn_s_barrier();
        if (t + 2 < NT) STAGE_T(t + 2);
        __builtin_amdgcn_s_setprio(1);
#pragma unroll
        for (int m = 0; m < 4; ++m)
#pragma unroll
            for (int n = 0; n < 4; ++n)
                acc[m][n] = __builtin_amdgcn_mfma_f32_16x16x32_bf16(av[m], bv[n], acc[m][n], 0, 0, 0);
        __builtin_amdgcn_s_setprio(0);
        // Counted wait: tile t+1 resident before next iteration reads it
        if (t + 2 < NT) {
            asm volatile("s_waitcnt vmcnt(4)" ::: "memory");   // in-flight 8 -> retire t+1
        } else if (t + 1 < NT) {
            asm volatile("s_waitcnt vmcnt(0)" ::: "memory");
        }
        __builtin_amdgcn_s_barrier();
    }
#undef STAGE_T

    // ---- Epilogue: bias + activation + LDS restage (round-9-proven), then
    // 256B-contiguous stores (write amplification 1x).
    // acc C/D mapping (proven): col = lane&15 (+nf*16+wn*64), row = (lane>>4)*4+reg.
    const int gate_id = bn >> 3;  // 0:tanh(Z) 1:sig(F) 2:sig(O), uniform per block
    {
        const int rl0 = wm * 64 + ((lane >> 4) << 2);
        const int cl0 = wn * 64 + lr;
#pragma unroll
        for (int nf = 0; nf < 4; ++nf) {
            const int col = cl0 + nf * 16;
            const float bb = bias[bn * BN + col];
#pragma unroll
            for (int mf = 0; mf < 4; ++mf) {
#pragma unroll
                for (int r = 0; r < 4; ++r) {
                    const int rl = rl0 + mf * 16 + r;          // local row 0..127
                    const float y = acc[mf][nf][r] + bb;
                    const float g = (gate_id == 0) ? fast_tanh(y) : fast_sigmoid(y);
                    const int phys = (col >> 3) ^ (rl & 7);    // 16B granule 0..15
                    LDSbuf[rl * 128 + (phys << 3) + (col & 7)] = f2bf(g);
                }
            }
        }
    }
    asm volatile("s_waitcnt lgkmcnt(0)" ::: "memory");
    __builtin_amdgcn_sched_barrier(0);
    __builtin_amdgcn_s_barrier();
    // Copy out: 128 rows x 256B; per instruction 4 rows x 256B contiguous.
    {
        const int gr = tid & 15;    // 16B granule within row
        const int rb = tid >> 4;    // 0..15
#pragma unroll
        for (int i = 0; i < 8; ++i) {
            const int rl = i * 16 + rb;
            const int phys = gr ^ (rl & 7);
            const bf16x8 v = *reinterpret_cast<const bf16x8*>(&LDSbuf[rl * 128 + (phys << 3)]);
            *reinterpret_cast<bf16x8*>(
                &gates[(size_t)(bm * BM + rl) * N_TOT + bn * BN + gr * 8]) = v;
        }
    }
#undef AS
#undef BS
}

// ---------------- chunked linear scan (fo-pool), vec2 over h ----------------
__global__ void __launch_bounds__(256) scan_phase1(const unsigned short* __restrict__ gates,
                                                   float* __restrict__ Aprod,
                                                   float* __restrict__ Cend) {
    const int t = blockIdx.x * 256 + threadIdx.x;  // chunk*8192 + b*512 + hp
    const int hp = t & 511;
    const int b  = (t >> 9) & (BATCH - 1);
    const int chunk = t >> 13;
    float c0 = 0.f, c1 = 0.f, a0 = 1.f, a1 = 1.f;
    const int m0 = chunk * (CHLEN * BATCH) + b;
    const unsigned short* gz = gates + (size_t)m0 * N_TOT + hp * 2;
#pragma unroll 4
    for (int i = 0; i < CHLEN; ++i) {
        const unsigned short* p = gz + (size_t)i * BATCH * N_TOT;
        const unsigned int zz = *reinterpret_cast<const unsigned int*>(p);
        const unsigned int ff = *reinterpret_cast<const unsigned int*>(p + HID);
        const float z0 = bf2f(zz & 0xffffu), z1 = bf2f(zz >> 16);
        const float f0 = bf2f(ff & 0xffffu), f1 = bf2f(ff >> 16);
        const float o0 = 1.f - f0, o1 = 1.f - f1;
        c0 = f0 * z0 + o0 * c0;  c1 = f1 * z1 + o1 * c1;
        a0 *= o0;                a1 *= o1;
    }
    const int idx = chunk * (BATCH * HID) + b * HID + hp * 2;
    *reinterpret_cast<float2*>(&Aprod[idx]) = make_float2(a0, a1);
    *reinterpret_cast<float2*>(&Cend[idx])  = make_float2(c0, c1);
}

__global__ void __launch_bounds__(256) scan_combine(const float* __restrict__ Aprod,
                                                    const float* __restrict__ Cend,
                                                    const float* __restrict__ hidden,
                                                    float* __restrict__ Cstart,
                                                    float* __restrict__ c_last) {
    const int t = blockIdx.x * 256 + threadIdx.x;  // b*1024 + h
    float c = hidden[t];
#pragma unroll
    for (int j = 0; j < NCHUNK; ++j) {
        const int idx = j * (BATCH * HID) + t;
        Cstart[idx] = c;
        c = Aprod[idx] * c + Cend[idx];
    }
    c_last[t] = c;
}

__global__ void __launch_bounds__(256) scan_phase3(const unsigned short* __restrict__ gates,
                                                   const float* __restrict__ Cstart,
                                                   float* __restrict__ Hout) {
    const int t = blockIdx.x * 256 + threadIdx.x;
    const int hp = t & 511;
    const int b  = (t >> 9) & (BATCH - 1);
    const int chunk = t >> 13;
    const int idx = chunk * (BATCH * HID) + b * HID + hp * 2;
    float2 cs = *reinterpret_cast<const float2*>(&Cstart[idx]);
    float c0 = cs.x, c1 = cs.y;
    const int m0 = chunk * (CHLEN * BATCH) + b;
    const unsigned short* gz = gates + (size_t)m0 * N_TOT + hp * 2;
#pragma unroll 4
    for (int i = 0; i < CHLEN; ++i) {
        const unsigned short* p = gz + (size_t)i * BATCH * N_TOT;
        const unsigned int zz = *reinterpret_cast<const unsigned int*>(p);
        const unsigned int ff = *reinterpret_cast<const unsigned int*>(p + HID);
        const unsigned int oo = *reinterpret_cast<const unsigned int*>(p + 2 * HID);
        const float z0 = bf2f(zz & 0xffffu), z1 = bf2f(zz >> 16);
        const float f0 = bf2f(ff & 0xffffu), f1 = bf2f(ff >> 16);
        const float g0 = bf2f(oo & 0xffffu), g1 = bf2f(oo >> 16);
        c0 = f0 * z0 + (1.f - f0) * c0;
        c1 = f1 * z1 + (1.f - f1) * c1;
        const int m = m0 + i * BATCH;
        *reinterpret_cast<float2*>(&Hout[(size_t)m * HID + hp * 2]) = make_float2(g0 * c0, g1 * c1);
    }
}

// ---------------- launch ----------------
extern "C" void kernel_launch(void* const* d_in, const int* in_sizes, int n_in,
                              void* d_out, int out_size, void* d_ws, size_t ws_size,
                              hipStream_t stream) {
    const float* X      = (const float*)d_in[0];
    const float* hidden = (const float*)d_in[1];
    const float* W      = (const float*)d_in[2];
    const float* bias   = (const float*)d_in[3];
    float* out    = (float*)d_out;
    float* c_last = out + (size_t)M_TOT * HID;   // outputs: H_out then C[-1:]

    char* ws = (char*)d_ws;
    unsigned short* Xb    = (unsigned short*)ws;                                // 64 MiB
    unsigned short* Wb    = (unsigned short*)(ws + (size_t)M_TOT * K_TOT * 2);  // 6 MiB
    unsigned short* gates = Wb + (size_t)N_TOT * K_TOT;                         // 192 MiB bf16
    float* Aprod  = (float*)(gates + (size_t)M_TOT * N_TOT);
    float* Cend   = Aprod + (size_t)NCHUNK * BATCH * HID;
    float* Cstart = Cend  + (size_t)NCHUNK * BATCH * HID;

    cvt_both<<<dim3(2560), dim3(256), 0, stream>>>(X, W, Xb, Wb);
    gemm_gates<<<dim3(NWG), dim3(256), 0, stream>>>(Xb, Wb, bias, gates);
    scan_phase1<<<dim3(1024), dim3(256), 0, stream>>>(gates, Aprod, Cend);
    scan_combine<<<dim3(64), dim3(256), 0, stream>>>(Aprod, Cend, hidden, Cstart, c_last);
    scan_phase3<<<dim3(1024), dim3(256), 0, stream>>>(gates, Cstart, out);
}